// Round 6
// baseline (1438.234 us; speedup 1.0000x reference)
//
#include <hip/hip_runtime.h>
#include <cstdint>
#include <cstddef>

#define NN   4096
#define LLC  50

__device__ __forceinline__ float bf2f(unsigned short u) {
    return __uint_as_float(((unsigned)u) << 16);
}
__device__ __forceinline__ unsigned short f2bf(float x) {
    unsigned b = __float_as_uint(x);
    return (unsigned short)((b + 0x7fffu + ((b >> 16) & 1u)) >> 16);
}

#if __has_builtin(__builtin_amdgcn_sdot4)
#define SDOT4(a, b, c) __builtin_amdgcn_sdot4((int)(a), (int)(b), (c), false)
#else
__device__ __forceinline__ int sdot4_sw(unsigned a, unsigned b, int c) {
    c += (int)(signed char)(a) * (int)(signed char)(b);
    c += (int)(signed char)(a >> 8) * (int)(signed char)(b >> 8);
    c += (int)(signed char)(a >> 16) * (int)(signed char)(b >> 16);
    c += (int)(signed char)(a >> 24) * (int)(signed char)(b >> 24);
    return c;
}
#define SDOT4(a, b, c) sdot4_sw((a), (b), (c))
#endif

// sum across 64 lanes via DPP (VALU pipe); total lands in lane 63
#define DPPADD(v, ctrl, rmask) \
    ((v) + __builtin_amdgcn_update_dpp(0, (v), (ctrl), (rmask), 0xf, true))
__device__ __forceinline__ int wred64(int v) {
    v = DPPADD(v, 0x111, 0xf);   // row_shr:1
    v = DPPADD(v, 0x112, 0xf);   // row_shr:2
    v = DPPADD(v, 0x114, 0xf);   // row_shr:4
    v = DPPADD(v, 0x118, 0xf);   // row_shr:8
    v = DPPADD(v, 0x142, 0xa);   // row_bcast15
    v = DPPADD(v, 0x143, 0xc);   // row_bcast31 -> lane63=total
    return v;
}

// ---- W_hh fp32 -> int8 (x8192), REPACKED for lane-contiguous rnn loads -----
// Wp dword p = row*1024 + k4*256 + lane*4 + i holds k-dword k = lane*16+k4*4+i.
__global__ __launch_bounds__(256) void k_w8(const float* __restrict__ W,
                                            uint4* __restrict__ out) {
    unsigned T = blockIdx.x * 256 + threadIdx.x;     // [0, 1M)
    unsigned row = T >> 8, rem = T & 255;
    unsigned k4 = rem >> 6, lane = rem & 63;
    unsigned k0 = lane * 16 + k4 * 4;                // first input dword
    const float* src = W + ((size_t)row * 1024 + k0) * 4;  // 16 consecutive floats
    unsigned q[4];
#pragma unroll
    for (int i = 0; i < 4; ++i) {
        float4 w = *(const float4*)(src + i * 4);
        int q0 = (int)rintf(fminf(fmaxf(w.x * 8192.f, -127.f), 127.f));
        int q1 = (int)rintf(fminf(fmaxf(w.y * 8192.f, -127.f), 127.f));
        int q2 = (int)rintf(fminf(fmaxf(w.z * 8192.f, -127.f), 127.f));
        int q3 = (int)rintf(fminf(fmaxf(w.w * 8192.f, -127.f), 127.f));
        q[i] = (q0 & 0xff) | ((q1 & 0xff) << 8) | ((q2 & 0xff) << 16) | ((q3 & 0xff) << 24);
    }
    out[(size_t)row * 256 + k4 * 64 + lane] = make_uint4(q[0], q[1], q[2], q[3]);
}

// ---- filt1 = fea@W1, filt2 = fea@W2  -> bf16 [16384,128] -------------------
__global__ __launch_bounds__(128) void k_filt(const float* __restrict__ fea,
                                              const float* __restrict__ W1,
                                              const float* __restrict__ W2,
                                              unsigned short* __restrict__ f1,
                                              unsigned short* __restrict__ f2) {
    __shared__ float sfea[16][128];
    int t = threadIdx.x;
    int rb = blockIdx.x * 16;
    for (int r = 0; r < 16; ++r) sfea[r][t] = fea[(size_t)(rb + r) * 128 + t];
    __syncthreads();
    float a1[16], a2[16];
#pragma unroll
    for (int r = 0; r < 16; ++r) { a1[r] = 0.f; a2[r] = 0.f; }
    for (int c = 0; c < 128; c += 4) {
        float w10 = W1[(c + 0) * 128 + t], w11 = W1[(c + 1) * 128 + t];
        float w12 = W1[(c + 2) * 128 + t], w13 = W1[(c + 3) * 128 + t];
        float w20 = W2[(c + 0) * 128 + t], w21 = W2[(c + 1) * 128 + t];
        float w22 = W2[(c + 2) * 128 + t], w23 = W2[(c + 3) * 128 + t];
#pragma unroll
        for (int r = 0; r < 16; ++r) {
            float4 f = *(const float4*)&sfea[r][c];
            a1[r] += f.x * w10 + f.y * w11 + f.z * w12 + f.w * w13;
            a2[r] += f.x * w20 + f.y * w21 + f.z * w22 + f.w * w23;
        }
    }
#pragma unroll
    for (int r = 0; r < 16; ++r) {
        f1[(size_t)(rb + r) * 128 + t] = f2bf(a1[r]);
        f2[(size_t)(rb + r) * 128 + t] = f2bf(a2[r]);
    }
}

// ---- CSR build: LDS-privatized histogram -> scan -> packed scatter ----------
__global__ __launch_bounds__(256) void k_hist(const int* __restrict__ i0, const int* __restrict__ i1,
                                              const int* __restrict__ i2, const int* __restrict__ i3,
                                              int* __restrict__ counts) {
    __shared__ int lc[4096];
    int t = threadIdx.x;
#pragma unroll
    for (int i = 0; i < 16; ++i) lc[t + i * 256] = 0;
    __syncthreads();
    unsigned blk = blockIdx.x;              // 256: s = blk>>4, chunk = blk&15
    unsigned s = blk >> 4, ch = blk & 15;
    unsigned m = s >> 2, b = s & 3;
    const int* ip = (m == 0) ? i0 : (m == 1) ? i1 : (m == 2) ? i2 : i3;
    unsigned base = b * 131072u + ch * 4096u;
#pragma unroll
    for (int i = 0; i < 16; ++i) {
        int r = ip[base + t + i * 256];
        atomicAdd(&lc[r], 1);
    }
    __syncthreads();
    int* cs = counts + s * 4096;
#pragma unroll
    for (int i = 0; i < 16; ++i) {
        int v = lc[t + i * 256];
        if (v) atomicAdd(cs + t + i * 256, v);
    }
}

__global__ __launch_bounds__(256) void k_scan(const int* __restrict__ counts,
                                              int* __restrict__ rowptr,
                                              int* __restrict__ cursor) {
    int s = blockIdx.x, t = threadIdx.x;
    int loc[16];
    int base = t * 16;
    const int* cs = counts + s * 4096;
    int run = 0;
#pragma unroll
    for (int i = 0; i < 16; ++i) { loc[i] = run; run += cs[base + i]; }
    int total = run;
    int lane = t & 63, wv = t >> 6;
    int v = total;
#pragma unroll
    for (int d = 1; d < 64; d <<= 1) { int u = __shfl_up(v, d, 64); if (lane >= d) v += u; }
    __shared__ int wt[4];
    if (lane == 63) wt[wv] = v;
    __syncthreads();
    int pre = v - total;
    for (int i = 0; i < wv; ++i) pre += wt[i];
    int* rp = rowptr + s * 4097;
    int* cu = cursor + s * 4096;
#pragma unroll
    for (int i = 0; i < 16; ++i) { rp[base + i] = pre + loc[i]; cu[base + i] = pre + loc[i]; }
    if (t == 255) rp[4096] = pre + total;
}

__global__ __launch_bounds__(256) void k_scatter(const int* __restrict__ i0, const int* __restrict__ i1,
                                                 const int* __restrict__ i2, const int* __restrict__ i3,
                                                 const float* __restrict__ v0, const float* __restrict__ v1,
                                                 const float* __restrict__ v2, const float* __restrict__ v3,
                                                 const float* __restrict__ d1, const float* __restrict__ d2,
                                                 int* __restrict__ cursor,
                                                 unsigned* __restrict__ ep) {
    unsigned gid = blockIdx.x * 256 + threadIdx.x;
    unsigned s = gid >> 16, e = gid & 65535;
    unsigned m = s >> 2, b = s & 3;
    const int* ip = (m == 0) ? i0 : (m == 1) ? i1 : (m == 2) ? i2 : i3;
    const float* vp = (m == 0) ? v0 : (m == 1) ? v1 : (m == 2) ? v2 : v3;
    int r = ip[(size_t)b * 131072 + e];
    int c = ip[(size_t)b * 131072 + 65536 + e];
    float v = vp[(size_t)b * 65536 + e];
    if (m == 1) v *= d1[c];
    if (m == 3) v *= d2[c];
    int pos = atomicAdd(cursor + s * 4096 + r, 1);
    ep[(size_t)s * 65536 + pos] = ((unsigned)c << 16) | (unsigned)f2bf(v);   // col|bf16(val)
}

// ---- pass 1: y1 = inv1@filt1, y2 = inv2@filt2 (gather, no atomics) ---------
__global__ __launch_bounds__(128) void k_gather1(const int* __restrict__ rowptr,
                                                 const unsigned* __restrict__ ep,
                                                 const unsigned short* __restrict__ filt1,
                                                 const unsigned short* __restrict__ filt2,
                                                 unsigned short* __restrict__ y1,
                                                 unsigned short* __restrict__ y2) {
    unsigned blk = blockIdx.x;                 // 32768: [mm][row][b]
    unsigned b = blk & 3, row = (blk >> 2) & 4095, mm = blk >> 14;
    int s = (mm ? 8 : 0) + (int)b;
    const unsigned short* X = mm ? filt2 : filt1;
    unsigned short* Y = mm ? y2 : y1;
    int f = threadIdx.x;
    const int* rp = rowptr + s * 4097;
    int e0 = rp[row], e1 = rp[row + 1];
    float acc = 0.f;
    for (int e = e0; e < e1; ++e) {
        unsigned pp = ep[(size_t)s * 65536 + e];
        float v = bf2f((unsigned short)(pp & 0xffffu));
        int c = (int)(pp >> 16);
        acc += v * bf2f(X[((size_t)b * 4096 + c) * 128 + f]);
    }
    Y[((size_t)b * 4096 + row) * 128 + f] = f2bf(acc);
}

// ---- pass 2: res = phi1@(d1*y1) + phi2@(d2*y2) -----------------------------
__global__ __launch_bounds__(128) void k_gather2(const int* __restrict__ rowptr,
                                                 const unsigned* __restrict__ ep,
                                                 const unsigned short* __restrict__ y1,
                                                 const unsigned short* __restrict__ y2,
                                                 float* __restrict__ res) {
    unsigned blk = blockIdx.x;                 // 16384
    unsigned b = blk & 3, row = blk >> 2;
    int f = threadIdx.x;
    float acc = 0.f;
    {
        int s = 4 + (int)b;
        const int* rp = rowptr + s * 4097;
        int e0 = rp[row], e1 = rp[row + 1];
        for (int e = e0; e < e1; ++e) {
            unsigned pp = ep[(size_t)s * 65536 + e];
            float v = bf2f((unsigned short)(pp & 0xffffu));
            int c = (int)(pp >> 16);
            acc += v * bf2f(y1[((size_t)b * 4096 + c) * 128 + f]);
        }
    }
    {
        int s = 12 + (int)b;
        const int* rp = rowptr + s * 4097;
        int e0 = rp[row], e1 = rp[row + 1];
        for (int e = e0; e < e1; ++e) {
            unsigned pp = ep[(size_t)s * 65536 + e];
            float v = bf2f((unsigned short)(pp & 0xffffu));
            int c = (int)(pp >> 16);
            acc += v * bf2f(y2[((size_t)b * 4096 + c) * 128 + f]);
        }
    }
    res[((size_t)b * 4096 + row) * 128 + f] = acc;
}

// ---- xproj[p=l*4+b][n] -------------------------------------------------------
__global__ __launch_bounds__(256) void k_xproj(const float* __restrict__ item_emb,
                                               const int* __restrict__ joblst,
                                               const float* __restrict__ W_ih,
                                               const float* __restrict__ b_ih,
                                               const float* __restrict__ b_hh,
                                               float* __restrict__ xp) {
    __shared__ float sx[8][128];
    int t = threadIdx.x;
    int n = blockIdx.x * 256 + t;
    int p0 = blockIdx.y * 8;
#pragma unroll
    for (int i = 0; i < 4; ++i) {
        int e2 = t + i * 256;
        int rr = e2 >> 7, c = e2 & 127;
        int p = p0 + rr;
        int b = p & 3, l = p >> 2;
        int j = joblst[b * LLC + l];
        sx[rr][c] = item_emb[(size_t)j * 128 + c];
    }
    __syncthreads();
    float acc[8];
#pragma unroll
    for (int r = 0; r < 8; ++r) acc[r] = 0.f;
    const float* wn = W_ih + (size_t)n * 128;
    for (int c = 0; c < 128; c += 4) {
        float4 w = *(const float4*)(wn + c);
#pragma unroll
        for (int r = 0; r < 8; ++r) {
            float4 xr = *(const float4*)&sx[r][c];
            acc[r] += xr.x * w.x + xr.y * w.y + xr.z * w.z + xr.w * w.w;
        }
    }
    float bias = b_ih[n] + b_hh[n];
#pragma unroll
    for (int r = 0; r < 8; ++r) xp[(size_t)(p0 + r) * NN + n] = acc[r] + bias;
}

// ---- whole RNN: ONE cooperative kernel, FENCE-FREE barrier -------------------
// 256 blocks x 256 thr; W int8 in VGPRs all 50 steps.
// hq visibility: agent-scope atomic stores (sc1 write-through to coherence
// point) + agent-scope atomic loads (bypass L1/L2) -- NO __threadfence (round
// 5's 20us/step was 512 L2 writeback/inv cache ops per step).
// Barrier: 8 padded group counters (32 blocks each) -> 1 root (8 RMW/step);
// spin s_sleep(2).
// hq dword layout == LDS phys layout: idx = k4*1024 + b*256 + lane*4 + j,
// where logical h-dword hk = lane*16 + k4*4 + j (h elems 4hk..4hk+3).
// Staging is an identity copy (coalesced global, stride-1 LDS); fragment
// reads are lane-consecutive uint4 (16B stride: conflict-free).
__global__ __launch_bounds__(256) void k_rnn_all(const uint4* __restrict__ Wp,
                                                 const float* __restrict__ xp,
                                                 unsigned* __restrict__ hq,   // [2][4096]
                                                 float* __restrict__ hfin,
                                                 int* __restrict__ bar) {     // [257] ints
    __shared__ unsigned hs[4096];              // 16KB staged h
    __shared__ int red[4][16];
    __shared__ unsigned char hpk[4][4][4];     // [wv][b][rr]
    int t = threadIdx.x;
    int lane = t & 63, wv = t >> 6;
    int blk = blockIdx.x;
    int row_base = ((blk & 7) * 32 + (blk >> 3)) * 16;   // XCD-sliced: 512 rows/XCD
    int wrow = row_base + wv * 4;

    // W fragment -> registers, once (64 VGPRs; 2MB/XCD slice L2-resident)
    uint4 W[4][4];
#pragma unroll
    for (int r = 0; r < 4; ++r)
#pragma unroll
        for (int k4 = 0; k4 < 4; ++k4)
            W[r][k4] = Wp[(size_t)(wrow + r) * 256 + k4 * 64 + lane];

    const float SC = 1.f / (8192.f * 127.f);

    for (int l = 0; l < LLC; ++l) {
        if (l > 0) {
            // stage h: 16 coalesced agent loads -> stride-1 LDS
            const unsigned* src = hq + (size_t)((l - 1) & 1) * 4096;
            unsigned sval[16];
#pragma unroll
            for (int k = 0; k < 16; ++k)
                sval[k] = __hip_atomic_load(src + t + k * 256, __ATOMIC_RELAXED,
                                            __HIP_MEMORY_SCOPE_AGENT);
#pragma unroll
            for (int k = 0; k < 16; ++k) hs[t + k * 256] = sval[k];
            __syncthreads();

            uint4 H[4][4];
#pragma unroll
            for (int b = 0; b < 4; ++b)
#pragma unroll
                for (int k4 = 0; k4 < 4; ++k4)
                    H[b][k4] = ((const uint4*)hs)[k4 * 256 + b * 64 + lane];
            int acc[4][4];
#pragma unroll
            for (int r = 0; r < 4; ++r)
#pragma unroll
                for (int b = 0; b < 4; ++b) acc[r][b] = 0;
#pragma unroll
            for (int k4 = 0; k4 < 4; ++k4)
#pragma unroll
                for (int r = 0; r < 4; ++r)
#pragma unroll
                    for (int b = 0; b < 4; ++b) {
                        acc[r][b] = SDOT4(W[r][k4].x, H[b][k4].x, acc[r][b]);
                        acc[r][b] = SDOT4(W[r][k4].y, H[b][k4].y, acc[r][b]);
                        acc[r][b] = SDOT4(W[r][k4].z, H[b][k4].z, acc[r][b]);
                        acc[r][b] = SDOT4(W[r][k4].w, H[b][k4].w, acc[r][b]);
                    }
#pragma unroll
            for (int r = 0; r < 4; ++r)
#pragma unroll
                for (int b = 0; b < 4; ++b) acc[r][b] = wred64(acc[r][b]);
            if (lane == 63) {
#pragma unroll
                for (int b = 0; b < 4; ++b) {
                    int4 q = { acc[0][b], acc[1][b], acc[2][b], acc[3][b] };
                    *(int4*)&red[wv][b * 4] = q;   // red[wv][b*4+rr]
                }
            }
        }
        // tail: 16 lanes/wave produce 4 rows x 4 batches (same-wave LDS dep)
        if (lane < 16) {
            int b = lane >> 2, rr = lane & 3;
            int row = wrow + rr;
            float a = (l > 0) ? (float)red[wv][lane] * SC : 0.f;
            float pre = a + xp[(size_t)(l * 4 + b) * NN + row];
            float hnew = tanhf(pre);
            if (l == LLC - 1) hfin[(size_t)b * NN + row] = hnew;
            int q = (int)rintf(hnew * 127.f);
            hpk[wv][b][rr] = (unsigned char)(q & 0xff);
        }
        if (l < LLC - 1) {
            if (lane < 4) {
                int b = lane;
                unsigned d = *(const unsigned*)&hpk[wv][b][0];
                int hk = (row_base >> 2) + wv;          // h-dword index (rows 4hk..4hk+3)
                int phys = ((hk >> 2) & 3) * 1024 + b * 256 + (hk >> 4) * 4 + (hk & 3);
                __hip_atomic_store(hq + (size_t)(l & 1) * 4096 + phys, d,
                                   __ATOMIC_RELEASE, __HIP_MEMORY_SCOPE_AGENT);
            }
            // ---- fence-free grid barrier ----
            __syncthreads();                   // drains all waves' stores (vmcnt 0)
            if (t == 0) {
                int g = blk & 7;
                int old = __hip_atomic_fetch_add(&bar[g * 32], 1, __ATOMIC_ACQ_REL,
                                                 __HIP_MEMORY_SCOPE_AGENT);
                if ((old & 31) == 31)          // last of 32-block group this step
                    __hip_atomic_fetch_add(&bar[256], 1, __ATOMIC_ACQ_REL,
                                           __HIP_MEMORY_SCOPE_AGENT);
                int target = 8 * (l + 1);
                while (__hip_atomic_load(&bar[256], __ATOMIC_ACQUIRE,
                                         __HIP_MEMORY_SCOPE_AGENT) < target)
                    __builtin_amdgcn_s_sleep(2);
            }
            __syncthreads();
        }
    }
}

// ---- out[b,n,k] = sigmoid( gelu(res.dW[k]+db) * gelu(Emb) ), LDS-staged ----
__global__ __launch_bounds__(256) void k_final(const float* __restrict__ res,
                                               const float* __restrict__ dW,
                                               const float* __restrict__ db,
                                               const float* __restrict__ hfin,
                                               float* __restrict__ out) {
    __shared__ float4 sres4[512];          // 16 rows x 128
    __shared__ float sdw[10 * 132];        // pad 132: kills bank conflict
    int t = threadIdx.x;
    int row0 = blockIdx.x * 16;
    {
        const float4* src = (const float4*)(res + (size_t)row0 * 128);
        sres4[t] = src[t];
        sres4[t + 256] = src[t + 256];
    }
    for (int i = t; i < 1280; i += 256) { int k = i >> 7, c = i & 127; sdw[k * 132 + c] = dW[i]; }
    __syncthreads();
    int r = t >> 4, k = t & 15;
    if (k < 10) {
        const float* rr = (const float*)sres4 + r * 128;
        const float* wk = sdw + k * 132;
        float acc = 0.f;
#pragma unroll
        for (int c = 0; c < 128; c += 4) {
            float4 a = *(const float4*)(rr + c);
            float4 w = *(const float4*)(wk + c);
            acc += a.x * w.x + a.y * w.y + a.z * w.z + a.w * w.w;
        }
        float pre = acc + db[k];
        int grow = row0 + r;
        int b = grow >> 12, n = grow & 4095;
        float e = hfin[(size_t)b * NN + n];
        float g1 = 0.5f * pre * (1.f + erff(pre * 0.70710678118f));
        float ge = 0.5f * e * (1.f + erff(e * 0.70710678118f));
        out[(size_t)grow * 10 + k] = 1.f / (1.f + __expf(-g1 * ge));
    }
}

extern "C" void kernel_launch(void* const* d_in, const int* in_sizes, int n_in,
                              void* d_out, int out_size, void* d_ws, size_t ws_size,
                              hipStream_t stream) {
    const int*   phi1_idx = (const int*)d_in[0];
    const float* phi1_val = (const float*)d_in[1];
    const int*   inv1_idx = (const int*)d_in[2];
    const float* inv1_val = (const float*)d_in[3];
    const int*   phi2_idx = (const int*)d_in[4];
    const float* phi2_val = (const float*)d_in[5];
    const int*   inv2_idx = (const int*)d_in[6];
    const float* inv2_val = (const float*)d_in[7];
    const float* fea      = (const float*)d_in[8];
    const int*   joblst   = (const int*)d_in[9];
    const float* W1       = (const float*)d_in[10];
    const float* d1       = (const float*)d_in[11];
    const float* W2       = (const float*)d_in[12];
    const float* d2       = (const float*)d_in[13];
    const float* W_ih     = (const float*)d_in[14];
    const float* W_hh     = (const float*)d_in[15];
    const float* b_ih     = (const float*)d_in[16];
    const float* b_hh     = (const float*)d_in[17];
    const float* dense_W  = (const float*)d_in[18];
    const float* dense_b  = (const float*)d_in[19];
    const float* item_emb = (const float*)d_in[20];

    float* ws = (float*)d_ws;                       // slot = 4B
    unsigned short* filt1 = (unsigned short*)ws;            // 1,048,576 slots
    unsigned short* filt2 = (unsigned short*)(ws + 1048576);
    unsigned short* y1    = (unsigned short*)(ws + 2097152);
    unsigned short* y2    = (unsigned short*)(ws + 3145728);
    float* res  = ws + 4194304;                     // 2,097,152 slots
    float* xp   = ws + 6291456;                     // 819,200
    float* hfin = ws + 7110656;                     // 16,384
    unsigned* hq  = (unsigned*)(ws + 7127040);      // 8,192 (2 x 4096 dwords)
    uint4* w8p = (uint4*)(ws + 7135232);            // 16MB repacked int8 W
    int*   counts = (int*)(ws + 11329536);          // 65,536
    int*   rowptr = (int*)(ws + 11395072);          // 65,552
    int*   cursor = (int*)(ws + 11460624);          // 65,536
    unsigned* ep  = (unsigned*)(ws + 11526160);     // 1,048,576 (packed col|val)
    int*   bar    = (int*)(ws + 12574736);          // 257 ints (barrier counters)

    hipMemsetAsync(counts, 0, 16 * 4096 * sizeof(int), stream);
    hipMemsetAsync(bar, 0, 2048, stream);

    k_w8<<<4096, 256, 0, stream>>>(W_hh, w8p);
    k_filt<<<1024, 128, 0, stream>>>(fea, W1, W2, filt1, filt2);
    k_xproj<<<dim3(16, 25), 256, 0, stream>>>(item_emb, joblst, W_ih, b_ih, b_hh, xp);

    k_hist<<<256, 256, 0, stream>>>(inv1_idx, phi1_idx, inv2_idx, phi2_idx, counts);
    k_scan<<<16, 256, 0, stream>>>(counts, rowptr, cursor);
    k_scatter<<<4096, 256, 0, stream>>>(inv1_idx, phi1_idx, inv2_idx, phi2_idx,
                                        inv1_val, phi1_val, inv2_val, phi2_val,
                                        d1, d2, cursor, ep);

    k_gather1<<<32768, 128, 0, stream>>>(rowptr, ep, filt1, filt2, y1, y2);
    k_gather2<<<16384, 128, 0, stream>>>(rowptr, ep, y1, y2, res);

    {   // whole RNN: one cooperative launch, fence-free barrier between steps
        void* args[] = { (void*)&w8p, (void*)&xp, (void*)&hq, (void*)&hfin, (void*)&bar };
        hipLaunchCooperativeKernel((const void*)k_rnn_all, dim3(256), dim3(256),
                                   args, 0, stream);
    }

    k_final<<<1024, 256, 0, stream>>>(res, dense_W, dense_b, hfin, (float*)d_out);
}

// Round 7
// 601.849 us; speedup vs baseline: 2.3897x; 2.3897x over previous
//
#include <hip/hip_runtime.h>
#include <cstdint>
#include <cstddef>

#define NN   4096
#define LLC  50

__device__ __forceinline__ float bf2f(unsigned short u) {
    return __uint_as_float(((unsigned)u) << 16);
}
__device__ __forceinline__ unsigned short f2bf(float x) {
    unsigned b = __float_as_uint(x);
    return (unsigned short)((b + 0x7fffu + ((b >> 16) & 1u)) >> 16);
}

#if __has_builtin(__builtin_amdgcn_sdot4)
#define SDOT4(a, b, c) __builtin_amdgcn_sdot4((int)(a), (int)(b), (c), false)
#else
__device__ __forceinline__ int sdot4_sw(unsigned a, unsigned b, int c) {
    c += (int)(signed char)(a) * (int)(signed char)(b);
    c += (int)(signed char)(a >> 8) * (int)(signed char)(b >> 8);
    c += (int)(signed char)(a >> 16) * (int)(signed char)(b >> 16);
    c += (int)(signed char)(a >> 24) * (int)(signed char)(b >> 24);
    return c;
}
#define SDOT4(a, b, c) sdot4_sw((a), (b), (c))
#endif

// sum across 64 lanes via DPP (VALU pipe); total lands in lane 63
#define DPPADD(v, ctrl, rmask) \
    ((v) + __builtin_amdgcn_update_dpp(0, (v), (ctrl), (rmask), 0xf, true))
__device__ __forceinline__ int wred64(int v) {
    v = DPPADD(v, 0x111, 0xf);   // row_shr:1
    v = DPPADD(v, 0x112, 0xf);   // row_shr:2
    v = DPPADD(v, 0x114, 0xf);   // row_shr:4
    v = DPPADD(v, 0x118, 0xf);   // row_shr:8
    v = DPPADD(v, 0x142, 0xa);   // row_bcast15
    v = DPPADD(v, 0x143, 0xc);   // row_bcast31 -> lane63=total
    return v;
}

// ---- W_hh fp32 -> int8 (x8192), REPACKED for lane-contiguous rnn loads -----
// Wp dword p = row*1024 + k4*256 + lane*4 + i holds k-dword k = lane*16+k4*4+i.
__global__ __launch_bounds__(256) void k_w8(const float* __restrict__ W,
                                            uint4* __restrict__ out) {
    unsigned T = blockIdx.x * 256 + threadIdx.x;     // [0, 1M)
    unsigned row = T >> 8, rem = T & 255;
    unsigned k4 = rem >> 6, lane = rem & 63;
    unsigned k0 = lane * 16 + k4 * 4;                // first input dword
    const float* src = W + ((size_t)row * 1024 + k0) * 4;  // 16 consecutive floats
    unsigned q[4];
#pragma unroll
    for (int i = 0; i < 4; ++i) {
        float4 w = *(const float4*)(src + i * 4);
        int q0 = (int)rintf(fminf(fmaxf(w.x * 8192.f, -127.f), 127.f));
        int q1 = (int)rintf(fminf(fmaxf(w.y * 8192.f, -127.f), 127.f));
        int q2 = (int)rintf(fminf(fmaxf(w.z * 8192.f, -127.f), 127.f));
        int q3 = (int)rintf(fminf(fmaxf(w.w * 8192.f, -127.f), 127.f));
        q[i] = (q0 & 0xff) | ((q1 & 0xff) << 8) | ((q2 & 0xff) << 16) | ((q3 & 0xff) << 24);
    }
    out[(size_t)row * 256 + k4 * 64 + lane] = make_uint4(q[0], q[1], q[2], q[3]);
}

// ---- filt1 = fea@W1, filt2 = fea@W2  -> bf16 [16384,128] -------------------
__global__ __launch_bounds__(128) void k_filt(const float* __restrict__ fea,
                                              const float* __restrict__ W1,
                                              const float* __restrict__ W2,
                                              unsigned short* __restrict__ f1,
                                              unsigned short* __restrict__ f2) {
    __shared__ float sfea[16][128];
    int t = threadIdx.x;
    int rb = blockIdx.x * 16;
    for (int r = 0; r < 16; ++r) sfea[r][t] = fea[(size_t)(rb + r) * 128 + t];
    __syncthreads();
    float a1[16], a2[16];
#pragma unroll
    for (int r = 0; r < 16; ++r) { a1[r] = 0.f; a2[r] = 0.f; }
    for (int c = 0; c < 128; c += 4) {
        float w10 = W1[(c + 0) * 128 + t], w11 = W1[(c + 1) * 128 + t];
        float w12 = W1[(c + 2) * 128 + t], w13 = W1[(c + 3) * 128 + t];
        float w20 = W2[(c + 0) * 128 + t], w21 = W2[(c + 1) * 128 + t];
        float w22 = W2[(c + 2) * 128 + t], w23 = W2[(c + 3) * 128 + t];
#pragma unroll
        for (int r = 0; r < 16; ++r) {
            float4 f = *(const float4*)&sfea[r][c];
            a1[r] += f.x * w10 + f.y * w11 + f.z * w12 + f.w * w13;
            a2[r] += f.x * w20 + f.y * w21 + f.z * w22 + f.w * w23;
        }
    }
#pragma unroll
    for (int r = 0; r < 16; ++r) {
        f1[(size_t)(rb + r) * 128 + t] = f2bf(a1[r]);
        f2[(size_t)(rb + r) * 128 + t] = f2bf(a2[r]);
    }
}

// ---- CSR build: LDS-privatized histogram -> scan -> packed scatter ----------
__global__ __launch_bounds__(256) void k_hist(const int* __restrict__ i0, const int* __restrict__ i1,
                                              const int* __restrict__ i2, const int* __restrict__ i3,
                                              int* __restrict__ counts) {
    __shared__ int lc[4096];
    int t = threadIdx.x;
#pragma unroll
    for (int i = 0; i < 16; ++i) lc[t + i * 256] = 0;
    __syncthreads();
    unsigned blk = blockIdx.x;              // 256: s = blk>>4, chunk = blk&15
    unsigned s = blk >> 4, ch = blk & 15;
    unsigned m = s >> 2, b = s & 3;
    const int* ip = (m == 0) ? i0 : (m == 1) ? i1 : (m == 2) ? i2 : i3;
    unsigned base = b * 131072u + ch * 4096u;
#pragma unroll
    for (int i = 0; i < 16; ++i) {
        int r = ip[base + t + i * 256];
        atomicAdd(&lc[r], 1);
    }
    __syncthreads();
    int* cs = counts + s * 4096;
#pragma unroll
    for (int i = 0; i < 16; ++i) {
        int v = lc[t + i * 256];
        if (v) atomicAdd(cs + t + i * 256, v);
    }
}

__global__ __launch_bounds__(256) void k_scan(const int* __restrict__ counts,
                                              int* __restrict__ rowptr,
                                              int* __restrict__ cursor) {
    int s = blockIdx.x, t = threadIdx.x;
    int loc[16];
    int base = t * 16;
    const int* cs = counts + s * 4096;
    int run = 0;
#pragma unroll
    for (int i = 0; i < 16; ++i) { loc[i] = run; run += cs[base + i]; }
    int total = run;
    int lane = t & 63, wv = t >> 6;
    int v = total;
#pragma unroll
    for (int d = 1; d < 64; d <<= 1) { int u = __shfl_up(v, d, 64); if (lane >= d) v += u; }
    __shared__ int wt[4];
    if (lane == 63) wt[wv] = v;
    __syncthreads();
    int pre = v - total;
    for (int i = 0; i < wv; ++i) pre += wt[i];
    int* rp = rowptr + s * 4097;
    int* cu = cursor + s * 4096;
#pragma unroll
    for (int i = 0; i < 16; ++i) { rp[base + i] = pre + loc[i]; cu[base + i] = pre + loc[i]; }
    if (t == 255) rp[4096] = pre + total;
}

__global__ __launch_bounds__(256) void k_scatter(const int* __restrict__ i0, const int* __restrict__ i1,
                                                 const int* __restrict__ i2, const int* __restrict__ i3,
                                                 const float* __restrict__ v0, const float* __restrict__ v1,
                                                 const float* __restrict__ v2, const float* __restrict__ v3,
                                                 const float* __restrict__ d1, const float* __restrict__ d2,
                                                 int* __restrict__ cursor,
                                                 unsigned* __restrict__ ep) {
    unsigned gid = blockIdx.x * 256 + threadIdx.x;
    unsigned s = gid >> 16, e = gid & 65535;
    unsigned m = s >> 2, b = s & 3;
    const int* ip = (m == 0) ? i0 : (m == 1) ? i1 : (m == 2) ? i2 : i3;
    const float* vp = (m == 0) ? v0 : (m == 1) ? v1 : (m == 2) ? v2 : v3;
    int r = ip[(size_t)b * 131072 + e];
    int c = ip[(size_t)b * 131072 + 65536 + e];
    float v = vp[(size_t)b * 65536 + e];
    if (m == 1) v *= d1[c];
    if (m == 3) v *= d2[c];
    int pos = atomicAdd(cursor + s * 4096 + r, 1);
    ep[(size_t)s * 65536 + pos] = ((unsigned)c << 16) | (unsigned)f2bf(v);   // col|bf16(val)
}

// ---- pass 1: y1 = inv1@filt1, y2 = inv2@filt2 (gather, no atomics) ---------
__global__ __launch_bounds__(128) void k_gather1(const int* __restrict__ rowptr,
                                                 const unsigned* __restrict__ ep,
                                                 const unsigned short* __restrict__ filt1,
                                                 const unsigned short* __restrict__ filt2,
                                                 unsigned short* __restrict__ y1,
                                                 unsigned short* __restrict__ y2) {
    unsigned blk = blockIdx.x;                 // 32768: [mm][row][b]
    unsigned b = blk & 3, row = (blk >> 2) & 4095, mm = blk >> 14;
    int s = (mm ? 8 : 0) + (int)b;
    const unsigned short* X = mm ? filt2 : filt1;
    unsigned short* Y = mm ? y2 : y1;
    int f = threadIdx.x;
    const int* rp = rowptr + s * 4097;
    int e0 = rp[row], e1 = rp[row + 1];
    float acc = 0.f;
    for (int e = e0; e < e1; ++e) {
        unsigned pp = ep[(size_t)s * 65536 + e];
        float v = bf2f((unsigned short)(pp & 0xffffu));
        int c = (int)(pp >> 16);
        acc += v * bf2f(X[((size_t)b * 4096 + c) * 128 + f]);
    }
    Y[((size_t)b * 4096 + row) * 128 + f] = f2bf(acc);
}

// ---- pass 2: res = phi1@(d1*y1) + phi2@(d2*y2) -----------------------------
__global__ __launch_bounds__(128) void k_gather2(const int* __restrict__ rowptr,
                                                 const unsigned* __restrict__ ep,
                                                 const unsigned short* __restrict__ y1,
                                                 const unsigned short* __restrict__ y2,
                                                 float* __restrict__ res) {
    unsigned blk = blockIdx.x;                 // 16384
    unsigned b = blk & 3, row = blk >> 2;
    int f = threadIdx.x;
    float acc = 0.f;
    {
        int s = 4 + (int)b;
        const int* rp = rowptr + s * 4097;
        int e0 = rp[row], e1 = rp[row + 1];
        for (int e = e0; e < e1; ++e) {
            unsigned pp = ep[(size_t)s * 65536 + e];
            float v = bf2f((unsigned short)(pp & 0xffffu));
            int c = (int)(pp >> 16);
            acc += v * bf2f(y1[((size_t)b * 4096 + c) * 128 + f]);
        }
    }
    {
        int s = 12 + (int)b;
        const int* rp = rowptr + s * 4097;
        int e0 = rp[row], e1 = rp[row + 1];
        for (int e = e0; e < e1; ++e) {
            unsigned pp = ep[(size_t)s * 65536 + e];
            float v = bf2f((unsigned short)(pp & 0xffffu));
            int c = (int)(pp >> 16);
            acc += v * bf2f(y2[((size_t)b * 4096 + c) * 128 + f]);
        }
    }
    res[((size_t)b * 4096 + row) * 128 + f] = acc;
}

// ---- xproj[p=l*4+b][n] -------------------------------------------------------
__global__ __launch_bounds__(256) void k_xproj(const float* __restrict__ item_emb,
                                               const int* __restrict__ joblst,
                                               const float* __restrict__ W_ih,
                                               const float* __restrict__ b_ih,
                                               const float* __restrict__ b_hh,
                                               float* __restrict__ xp) {
    __shared__ float sx[8][128];
    int t = threadIdx.x;
    int n = blockIdx.x * 256 + t;
    int p0 = blockIdx.y * 8;
#pragma unroll
    for (int i = 0; i < 4; ++i) {
        int e2 = t + i * 256;
        int rr = e2 >> 7, c = e2 & 127;
        int p = p0 + rr;
        int b = p & 3, l = p >> 2;
        int j = joblst[b * LLC + l];
        sx[rr][c] = item_emb[(size_t)j * 128 + c];
    }
    __syncthreads();
    float acc[8];
#pragma unroll
    for (int r = 0; r < 8; ++r) acc[r] = 0.f;
    const float* wn = W_ih + (size_t)n * 128;
    for (int c = 0; c < 128; c += 4) {
        float4 w = *(const float4*)(wn + c);
#pragma unroll
        for (int r = 0; r < 8; ++r) {
            float4 xr = *(const float4*)&sx[r][c];
            acc[r] += xr.x * w.x + xr.y * w.y + xr.z * w.z + xr.w * w.w;
        }
    }
    float bias = b_ih[n] + b_hh[n];
#pragma unroll
    for (int r = 0; r < 8; ++r) xp[(size_t)(p0 + r) * NN + n] = acc[r] + bias;
}

// ---- whole RNN: ONE cooperative kernel, ALL-RELAXED barrier ------------------
// Rounds 5/6 both hit 20.7us/step because RELEASE/ACQ_REL/ACQUIRE agent-scope
// atomics on gfx9 embed buffer_wbl2/buffer_inv (L2 writeback/inv per op, per
// poll).  This round: every cross-block atomic is RELAXED (bare sc0.sc1
// global ops, write-through to the coherence point, zero cache maintenance).
// Ordering is structural: h stores are sc1 write-through; __syncthreads'
// s_waitcnt vmcnt(0) proves them complete at the coherence point before the
// arrive RMW is issued; the spin's dependent branch orders the h reloads.
__global__ __launch_bounds__(256) void k_rnn_all(const uint4* __restrict__ Wp,
                                                 const float* __restrict__ xp,
                                                 unsigned* __restrict__ hq,   // [2][4096]
                                                 float* __restrict__ hfin,
                                                 int* __restrict__ bar) {     // [257] ints
    __shared__ unsigned hs[4096];              // 16KB staged h
    __shared__ int red[4][16];
    __shared__ unsigned char hpk[4][4][4];     // [wv][b][rr]
    int t = threadIdx.x;
    int lane = t & 63, wv = t >> 6;
    int blk = blockIdx.x;
    int row_base = ((blk & 7) * 32 + (blk >> 3)) * 16;   // XCD-sliced: 512 rows/XCD
    int wrow = row_base + wv * 4;

    // W fragment -> registers, once (64 VGPRs; 2MB/XCD slice L2-resident)
    uint4 W[4][4];
#pragma unroll
    for (int r = 0; r < 4; ++r)
#pragma unroll
        for (int k4 = 0; k4 < 4; ++k4)
            W[r][k4] = Wp[(size_t)(wrow + r) * 256 + k4 * 64 + lane];

    const float SC = 1.f / (8192.f * 127.f);

    for (int l = 0; l < LLC; ++l) {
        if (l > 0) {
            // stage h: 16 coalesced relaxed-agent loads -> stride-1 LDS
            const unsigned* src = hq + (size_t)((l - 1) & 1) * 4096;
            unsigned sval[16];
#pragma unroll
            for (int k = 0; k < 16; ++k)
                sval[k] = __hip_atomic_load(src + t + k * 256, __ATOMIC_RELAXED,
                                            __HIP_MEMORY_SCOPE_AGENT);
#pragma unroll
            for (int k = 0; k < 16; ++k) hs[t + k * 256] = sval[k];
            __syncthreads();

            uint4 H[4][4];
#pragma unroll
            for (int b = 0; b < 4; ++b)
#pragma unroll
                for (int k4 = 0; k4 < 4; ++k4)
                    H[b][k4] = ((const uint4*)hs)[k4 * 256 + b * 64 + lane];
            int acc[4][4];
#pragma unroll
            for (int r = 0; r < 4; ++r)
#pragma unroll
                for (int b = 0; b < 4; ++b) acc[r][b] = 0;
#pragma unroll
            for (int k4 = 0; k4 < 4; ++k4)
#pragma unroll
                for (int r = 0; r < 4; ++r)
#pragma unroll
                    for (int b = 0; b < 4; ++b) {
                        acc[r][b] = SDOT4(W[r][k4].x, H[b][k4].x, acc[r][b]);
                        acc[r][b] = SDOT4(W[r][k4].y, H[b][k4].y, acc[r][b]);
                        acc[r][b] = SDOT4(W[r][k4].z, H[b][k4].z, acc[r][b]);
                        acc[r][b] = SDOT4(W[r][k4].w, H[b][k4].w, acc[r][b]);
                    }
#pragma unroll
            for (int r = 0; r < 4; ++r)
#pragma unroll
                for (int b = 0; b < 4; ++b) acc[r][b] = wred64(acc[r][b]);
            if (lane == 63) {
#pragma unroll
                for (int b = 0; b < 4; ++b) {
                    int4 q = { acc[0][b], acc[1][b], acc[2][b], acc[3][b] };
                    *(int4*)&red[wv][b * 4] = q;   // red[wv][b*4+rr]
                }
            }
        }
        // tail: 16 lanes/wave produce 4 rows x 4 batches (same-wave LDS dep)
        if (lane < 16) {
            int b = lane >> 2, rr = lane & 3;
            int row = wrow + rr;
            float a = (l > 0) ? (float)red[wv][lane] * SC : 0.f;
            float pre = a + xp[(size_t)(l * 4 + b) * NN + row];
            float hnew = tanhf(pre);
            if (l == LLC - 1) hfin[(size_t)b * NN + row] = hnew;
            int q = (int)rintf(hnew * 127.f);
            hpk[wv][b][rr] = (unsigned char)(q & 0xff);
        }
        if (l < LLC - 1) {
            if (lane < 4) {
                int b = lane;
                unsigned d = *(const unsigned*)&hpk[wv][b][0];
                int hk = (row_base >> 2) + wv;          // h-dword index (rows 4hk..4hk+3)
                int phys = ((hk >> 2) & 3) * 1024 + b * 256 + (hk >> 4) * 4 + (hk & 3);
                __hip_atomic_store(hq + (size_t)(l & 1) * 4096 + phys, d,
                                   __ATOMIC_RELAXED, __HIP_MEMORY_SCOPE_AGENT);
            }
            // ---- all-relaxed grid barrier (no wbl2/inv anywhere) ----
            __syncthreads();                   // s_waitcnt vmcnt(0): h at coherence pt
            if (t == 0) {
                int g = blk & 7;
                int old = __hip_atomic_fetch_add(&bar[g * 32], 1, __ATOMIC_RELAXED,
                                                 __HIP_MEMORY_SCOPE_AGENT);
                if ((old & 31) == 31)          // last of 32-block group this step
                    __hip_atomic_fetch_add(&bar[256], 1, __ATOMIC_RELAXED,
                                           __HIP_MEMORY_SCOPE_AGENT);
                int target = 8 * (l + 1);
                while (__hip_atomic_load(&bar[256], __ATOMIC_RELAXED,
                                         __HIP_MEMORY_SCOPE_AGENT) < target)
                    __builtin_amdgcn_s_sleep(2);
            }
            __syncthreads();
        }
    }
}

// ---- out[b,n,k] = sigmoid( gelu(res.dW[k]+db) * gelu(Emb) ), LDS-staged ----
__global__ __launch_bounds__(256) void k_final(const float* __restrict__ res,
                                               const float* __restrict__ dW,
                                               const float* __restrict__ db,
                                               const float* __restrict__ hfin,
                                               float* __restrict__ out) {
    __shared__ float4 sres4[512];          // 16 rows x 128
    __shared__ float sdw[10 * 132];        // pad 132: kills bank conflict
    int t = threadIdx.x;
    int row0 = blockIdx.x * 16;
    {
        const float4* src = (const float4*)(res + (size_t)row0 * 128);
        sres4[t] = src[t];
        sres4[t + 256] = src[t + 256];
    }
    for (int i = t; i < 1280; i += 256) { int k = i >> 7, c = i & 127; sdw[k * 132 + c] = dW[i]; }
    __syncthreads();
    int r = t >> 4, k = t & 15;
    if (k < 10) {
        const float* rr = (const float*)sres4 + r * 128;
        const float* wk = sdw + k * 132;
        float acc = 0.f;
#pragma unroll
        for (int c = 0; c < 128; c += 4) {
            float4 a = *(const float4*)(rr + c);
            float4 w = *(const float4*)(wk + c);
            acc += a.x * w.x + a.y * w.y + a.z * w.z + a.w * w.w;
        }
        float pre = acc + db[k];
        int grow = row0 + r;
        int b = grow >> 12, n = grow & 4095;
        float e = hfin[(size_t)b * NN + n];
        float g1 = 0.5f * pre * (1.f + erff(pre * 0.70710678118f));
        float ge = 0.5f * e * (1.f + erff(e * 0.70710678118f));
        out[(size_t)grow * 10 + k] = 1.f / (1.f + __expf(-g1 * ge));
    }
}

extern "C" void kernel_launch(void* const* d_in, const int* in_sizes, int n_in,
                              void* d_out, int out_size, void* d_ws, size_t ws_size,
                              hipStream_t stream) {
    const int*   phi1_idx = (const int*)d_in[0];
    const float* phi1_val = (const float*)d_in[1];
    const int*   inv1_idx = (const int*)d_in[2];
    const float* inv1_val = (const float*)d_in[3];
    const int*   phi2_idx = (const int*)d_in[4];
    const float* phi2_val = (const float*)d_in[5];
    const int*   inv2_idx = (const int*)d_in[6];
    const float* inv2_val = (const float*)d_in[7];
    const float* fea      = (const float*)d_in[8];
    const int*   joblst   = (const int*)d_in[9];
    const float* W1       = (const float*)d_in[10];
    const float* d1       = (const float*)d_in[11];
    const float* W2       = (const float*)d_in[12];
    const float* d2       = (const float*)d_in[13];
    const float* W_ih     = (const float*)d_in[14];
    const float* W_hh     = (const float*)d_in[15];
    const float* b_ih     = (const float*)d_in[16];
    const float* b_hh     = (const float*)d_in[17];
    const float* dense_W  = (const float*)d_in[18];
    const float* dense_b  = (const float*)d_in[19];
    const float* item_emb = (const float*)d_in[20];

    float* ws = (float*)d_ws;                       // slot = 4B
    unsigned short* filt1 = (unsigned short*)ws;            // 1,048,576 slots
    unsigned short* filt2 = (unsigned short*)(ws + 1048576);
    unsigned short* y1    = (unsigned short*)(ws + 2097152);
    unsigned short* y2    = (unsigned short*)(ws + 3145728);
    float* res  = ws + 4194304;                     // 2,097,152 slots
    float* xp   = ws + 6291456;                     // 819,200
    float* hfin = ws + 7110656;                     // 16,384
    unsigned* hq  = (unsigned*)(ws + 7127040);      // 8,192 (2 x 4096 dwords)
    uint4* w8p = (uint4*)(ws + 7135232);            // 16MB repacked int8 W
    int*   counts = (int*)(ws + 11329536);          // 65,536
    int*   rowptr = (int*)(ws + 11395072);          // 65,552
    int*   cursor = (int*)(ws + 11460624);          // 65,536
    unsigned* ep  = (unsigned*)(ws + 11526160);     // 1,048,576 (packed col|val)
    int*   bar    = (int*)(ws + 12574736);          // 257 ints (barrier counters)

    hipMemsetAsync(counts, 0, 16 * 4096 * sizeof(int), stream);
    hipMemsetAsync(bar, 0, 2048, stream);

    k_w8<<<4096, 256, 0, stream>>>(W_hh, w8p);
    k_filt<<<1024, 128, 0, stream>>>(fea, W1, W2, filt1, filt2);
    k_xproj<<<dim3(16, 25), 256, 0, stream>>>(item_emb, joblst, W_ih, b_ih, b_hh, xp);

    k_hist<<<256, 256, 0, stream>>>(inv1_idx, phi1_idx, inv2_idx, phi2_idx, counts);
    k_scan<<<16, 256, 0, stream>>>(counts, rowptr, cursor);
    k_scatter<<<4096, 256, 0, stream>>>(inv1_idx, phi1_idx, inv2_idx, phi2_idx,
                                        inv1_val, phi1_val, inv2_val, phi2_val,
                                        d1, d2, cursor, ep);

    k_gather1<<<32768, 128, 0, stream>>>(rowptr, ep, filt1, filt2, y1, y2);
    k_gather2<<<16384, 128, 0, stream>>>(rowptr, ep, y1, y2, res);

    {   // whole RNN: one cooperative launch, all-relaxed barrier between steps
        void* args[] = { (void*)&w8p, (void*)&xp, (void*)&hq, (void*)&hfin, (void*)&bar };
        hipLaunchCooperativeKernel((const void*)k_rnn_all, dim3(256), dim3(256),
                                   args, 0, stream);
    }

    k_final<<<1024, 256, 0, stream>>>(res, dense_W, dense_b, hfin, (float*)d_out);
}

// Round 8
// 548.452 us; speedup vs baseline: 2.6224x; 1.0974x over previous
//
#include <hip/hip_runtime.h>
#include <cstdint>
#include <cstddef>

#define NN   4096
#define LLC  50

__device__ __forceinline__ float bf2f(unsigned short u) {
    return __uint_as_float(((unsigned)u) << 16);
}
__device__ __forceinline__ unsigned short f2bf(float x) {
    unsigned b = __float_as_uint(x);
    return (unsigned short)((b + 0x7fffu + ((b >> 16) & 1u)) >> 16);
}

#if __has_builtin(__builtin_amdgcn_sdot4)
#define SDOT4(a, b, c) __builtin_amdgcn_sdot4((int)(a), (int)(b), (c), false)
#else
__device__ __forceinline__ int sdot4_sw(unsigned a, unsigned b, int c) {
    c += (int)(signed char)(a) * (int)(signed char)(b);
    c += (int)(signed char)(a >> 8) * (int)(signed char)(b >> 8);
    c += (int)(signed char)(a >> 16) * (int)(signed char)(b >> 16);
    c += (int)(signed char)(a >> 24) * (int)(signed char)(b >> 24);
    return c;
}
#define SDOT4(a, b, c) sdot4_sw((a), (b), (c))
#endif

// sum across 64 lanes via DPP (VALU pipe); total lands in lane 63
#define DPPADD(v, ctrl, rmask) \
    ((v) + __builtin_amdgcn_update_dpp(0, (v), (ctrl), (rmask), 0xf, true))
__device__ __forceinline__ int wred64(int v) {
    v = DPPADD(v, 0x111, 0xf);   // row_shr:1
    v = DPPADD(v, 0x112, 0xf);   // row_shr:2
    v = DPPADD(v, 0x114, 0xf);   // row_shr:4
    v = DPPADD(v, 0x118, 0xf);   // row_shr:8
    v = DPPADD(v, 0x142, 0xa);   // row_bcast15
    v = DPPADD(v, 0x143, 0xc);   // row_bcast31 -> lane63=total
    return v;
}

// ---- W_hh fp32 -> int8 (x8192), REPACKED for lane-contiguous rnn loads -----
// Wp dword p = row*1024 + k4*256 + lane*4 + i holds k-dword k = lane*16+k4*4+i.
__global__ __launch_bounds__(256) void k_w8(const float* __restrict__ W,
                                            uint4* __restrict__ out) {
    unsigned T = blockIdx.x * 256 + threadIdx.x;     // [0, 1M)
    unsigned row = T >> 8, rem = T & 255;
    unsigned k4 = rem >> 6, lane = rem & 63;
    unsigned k0 = lane * 16 + k4 * 4;                // first input dword
    const float* src = W + ((size_t)row * 1024 + k0) * 4;  // 16 consecutive floats
    unsigned q[4];
#pragma unroll
    for (int i = 0; i < 4; ++i) {
        float4 w = *(const float4*)(src + i * 4);
        int q0 = (int)rintf(fminf(fmaxf(w.x * 8192.f, -127.f), 127.f));
        int q1 = (int)rintf(fminf(fmaxf(w.y * 8192.f, -127.f), 127.f));
        int q2 = (int)rintf(fminf(fmaxf(w.z * 8192.f, -127.f), 127.f));
        int q3 = (int)rintf(fminf(fmaxf(w.w * 8192.f, -127.f), 127.f));
        q[i] = (q0 & 0xff) | ((q1 & 0xff) << 8) | ((q2 & 0xff) << 16) | ((q3 & 0xff) << 24);
    }
    out[(size_t)row * 256 + k4 * 64 + lane] = make_uint4(q[0], q[1], q[2], q[3]);
}

// ---- filt1 = fea@W1, filt2 = fea@W2  -> bf16 [16384,128] -------------------
__global__ __launch_bounds__(128) void k_filt(const float* __restrict__ fea,
                                              const float* __restrict__ W1,
                                              const float* __restrict__ W2,
                                              unsigned short* __restrict__ f1,
                                              unsigned short* __restrict__ f2) {
    __shared__ float sfea[16][128];
    int t = threadIdx.x;
    int rb = blockIdx.x * 16;
    for (int r = 0; r < 16; ++r) sfea[r][t] = fea[(size_t)(rb + r) * 128 + t];
    __syncthreads();
    float a1[16], a2[16];
#pragma unroll
    for (int r = 0; r < 16; ++r) { a1[r] = 0.f; a2[r] = 0.f; }
    for (int c = 0; c < 128; c += 4) {
        float w10 = W1[(c + 0) * 128 + t], w11 = W1[(c + 1) * 128 + t];
        float w12 = W1[(c + 2) * 128 + t], w13 = W1[(c + 3) * 128 + t];
        float w20 = W2[(c + 0) * 128 + t], w21 = W2[(c + 1) * 128 + t];
        float w22 = W2[(c + 2) * 128 + t], w23 = W2[(c + 3) * 128 + t];
#pragma unroll
        for (int r = 0; r < 16; ++r) {
            float4 f = *(const float4*)&sfea[r][c];
            a1[r] += f.x * w10 + f.y * w11 + f.z * w12 + f.w * w13;
            a2[r] += f.x * w20 + f.y * w21 + f.z * w22 + f.w * w23;
        }
    }
#pragma unroll
    for (int r = 0; r < 16; ++r) {
        f1[(size_t)(rb + r) * 128 + t] = f2bf(a1[r]);
        f2[(size_t)(rb + r) * 128 + t] = f2bf(a2[r]);
    }
}

// ---- CSR build: LDS-privatized histogram -> scan -> packed scatter ----------
__global__ __launch_bounds__(256) void k_hist(const int* __restrict__ i0, const int* __restrict__ i1,
                                              const int* __restrict__ i2, const int* __restrict__ i3,
                                              int* __restrict__ counts) {
    __shared__ int lc[4096];
    int t = threadIdx.x;
#pragma unroll
    for (int i = 0; i < 16; ++i) lc[t + i * 256] = 0;
    __syncthreads();
    unsigned blk = blockIdx.x;              // 256: s = blk>>4, chunk = blk&15
    unsigned s = blk >> 4, ch = blk & 15;
    unsigned m = s >> 2, b = s & 3;
    const int* ip = (m == 0) ? i0 : (m == 1) ? i1 : (m == 2) ? i2 : i3;
    unsigned base = b * 131072u + ch * 4096u;
#pragma unroll
    for (int i = 0; i < 16; ++i) {
        int r = ip[base + t + i * 256];
        atomicAdd(&lc[r], 1);
    }
    __syncthreads();
    int* cs = counts + s * 4096;
#pragma unroll
    for (int i = 0; i < 16; ++i) {
        int v = lc[t + i * 256];
        if (v) atomicAdd(cs + t + i * 256, v);
    }
}

__global__ __launch_bounds__(256) void k_scan(const int* __restrict__ counts,
                                              int* __restrict__ rowptr,
                                              int* __restrict__ cursor) {
    int s = blockIdx.x, t = threadIdx.x;
    int loc[16];
    int base = t * 16;
    const int* cs = counts + s * 4096;
    int run = 0;
#pragma unroll
    for (int i = 0; i < 16; ++i) { loc[i] = run; run += cs[base + i]; }
    int total = run;
    int lane = t & 63, wv = t >> 6;
    int v = total;
#pragma unroll
    for (int d = 1; d < 64; d <<= 1) { int u = __shfl_up(v, d, 64); if (lane >= d) v += u; }
    __shared__ int wt[4];
    if (lane == 63) wt[wv] = v;
    __syncthreads();
    int pre = v - total;
    for (int i = 0; i < wv; ++i) pre += wt[i];
    int* rp = rowptr + s * 4097;
    int* cu = cursor + s * 4096;
#pragma unroll
    for (int i = 0; i < 16; ++i) { rp[base + i] = pre + loc[i]; cu[base + i] = pre + loc[i]; }
    if (t == 255) rp[4096] = pre + total;
}

__global__ __launch_bounds__(256) void k_scatter(const int* __restrict__ i0, const int* __restrict__ i1,
                                                 const int* __restrict__ i2, const int* __restrict__ i3,
                                                 const float* __restrict__ v0, const float* __restrict__ v1,
                                                 const float* __restrict__ v2, const float* __restrict__ v3,
                                                 const float* __restrict__ d1, const float* __restrict__ d2,
                                                 int* __restrict__ cursor,
                                                 unsigned* __restrict__ ep) {
    unsigned gid = blockIdx.x * 256 + threadIdx.x;
    unsigned s = gid >> 16, e = gid & 65535;
    unsigned m = s >> 2, b = s & 3;
    const int* ip = (m == 0) ? i0 : (m == 1) ? i1 : (m == 2) ? i2 : i3;
    const float* vp = (m == 0) ? v0 : (m == 1) ? v1 : (m == 2) ? v2 : v3;
    int r = ip[(size_t)b * 131072 + e];
    int c = ip[(size_t)b * 131072 + 65536 + e];
    float v = vp[(size_t)b * 65536 + e];
    if (m == 1) v *= d1[c];
    if (m == 3) v *= d2[c];
    int pos = atomicAdd(cursor + s * 4096 + r, 1);
    ep[(size_t)s * 65536 + pos] = ((unsigned)c << 16) | (unsigned)f2bf(v);   // col|bf16(val)
}

// ---- pass 1: y1 = inv1@filt1, y2 = inv2@filt2 (gather, no atomics) ---------
__global__ __launch_bounds__(128) void k_gather1(const int* __restrict__ rowptr,
                                                 const unsigned* __restrict__ ep,
                                                 const unsigned short* __restrict__ filt1,
                                                 const unsigned short* __restrict__ filt2,
                                                 unsigned short* __restrict__ y1,
                                                 unsigned short* __restrict__ y2) {
    unsigned blk = blockIdx.x;                 // 32768: [mm][row][b]
    unsigned b = blk & 3, row = (blk >> 2) & 4095, mm = blk >> 14;
    int s = (mm ? 8 : 0) + (int)b;
    const unsigned short* X = mm ? filt2 : filt1;
    unsigned short* Y = mm ? y2 : y1;
    int f = threadIdx.x;
    const int* rp = rowptr + s * 4097;
    int e0 = rp[row], e1 = rp[row + 1];
    float acc = 0.f;
    for (int e = e0; e < e1; ++e) {
        unsigned pp = ep[(size_t)s * 65536 + e];
        float v = bf2f((unsigned short)(pp & 0xffffu));
        int c = (int)(pp >> 16);
        acc += v * bf2f(X[((size_t)b * 4096 + c) * 128 + f]);
    }
    Y[((size_t)b * 4096 + row) * 128 + f] = f2bf(acc);
}

// ---- pass 2: res = phi1@(d1*y1) + phi2@(d2*y2) -----------------------------
__global__ __launch_bounds__(128) void k_gather2(const int* __restrict__ rowptr,
                                                 const unsigned* __restrict__ ep,
                                                 const unsigned short* __restrict__ y1,
                                                 const unsigned short* __restrict__ y2,
                                                 float* __restrict__ res) {
    unsigned blk = blockIdx.x;                 // 16384
    unsigned b = blk & 3, row = blk >> 2;
    int f = threadIdx.x;
    float acc = 0.f;
    {
        int s = 4 + (int)b;
        const int* rp = rowptr + s * 4097;
        int e0 = rp[row], e1 = rp[row + 1];
        for (int e = e0; e < e1; ++e) {
            unsigned pp = ep[(size_t)s * 65536 + e];
            float v = bf2f((unsigned short)(pp & 0xffffu));
            int c = (int)(pp >> 16);
            acc += v * bf2f(y1[((size_t)b * 4096 + c) * 128 + f]);
        }
    }
    {
        int s = 12 + (int)b;
        const int* rp = rowptr + s * 4097;
        int e0 = rp[row], e1 = rp[row + 1];
        for (int e = e0; e < e1; ++e) {
            unsigned pp = ep[(size_t)s * 65536 + e];
            float v = bf2f((unsigned short)(pp & 0xffffu));
            int c = (int)(pp >> 16);
            acc += v * bf2f(y2[((size_t)b * 4096 + c) * 128 + f]);
        }
    }
    res[((size_t)b * 4096 + row) * 128 + f] = acc;
}

// ---- xproj[p=l*4+b][n] -------------------------------------------------------
__global__ __launch_bounds__(256) void k_xproj(const float* __restrict__ item_emb,
                                               const int* __restrict__ joblst,
                                               const float* __restrict__ W_ih,
                                               const float* __restrict__ b_ih,
                                               const float* __restrict__ b_hh,
                                               float* __restrict__ xp) {
    __shared__ float sx[8][128];
    int t = threadIdx.x;
    int n = blockIdx.x * 256 + t;
    int p0 = blockIdx.y * 8;
#pragma unroll
    for (int i = 0; i < 4; ++i) {
        int e2 = t + i * 256;
        int rr = e2 >> 7, c = e2 & 127;
        int p = p0 + rr;
        int b = p & 3, l = p >> 2;
        int j = joblst[b * LLC + l];
        sx[rr][c] = item_emb[(size_t)j * 128 + c];
    }
    __syncthreads();
    float acc[8];
#pragma unroll
    for (int r = 0; r < 8; ++r) acc[r] = 0.f;
    const float* wn = W_ih + (size_t)n * 128;
    for (int c = 0; c < 128; c += 4) {
        float4 w = *(const float4*)(wn + c);
#pragma unroll
        for (int r = 0; r < 8; ++r) {
            float4 xr = *(const float4*)&sx[r][c];
            acc[r] += xr.x * w.x + xr.y * w.y + xr.z * w.z + xr.w * w.w;
        }
    }
    float bias = b_ih[n] + b_hh[n];
#pragma unroll
    for (int r = 0; r < 8; ++r) xp[(size_t)(p0 + r) * NN + n] = acc[r] + bias;
}

// ---- whole RNN: persistent kernel, REGULAR launch, all-relaxed barrier ------
// Round 7 proved the all-relaxed barrier runs at 4.4us/step; cross-round
// accounting shows hipLaunchCooperativeKernel adds ~210us/replay outside the
// dispatch. Co-residency of a plain launch is structurally guaranteed: 64
// VGPR + 16.9KB LDS => >=8 blocks/CU capacity, 256 blocks <= capacity on any
// placement, so the spin barrier cannot deadlock.
__global__ __launch_bounds__(256) void k_rnn_all(const uint4* __restrict__ Wp,
                                                 const float* __restrict__ xp,
                                                 unsigned* __restrict__ hq,   // [2][4096]
                                                 float* __restrict__ hfin,
                                                 int* __restrict__ bar) {     // [257] ints
    __shared__ unsigned hs[4096];              // 16KB staged h
    __shared__ int red[4][16];
    __shared__ unsigned char hpk[4][4][4];     // [wv][b][rr]
    int t = threadIdx.x;
    int lane = t & 63, wv = t >> 6;
    int blk = blockIdx.x;
    int row_base = ((blk & 7) * 32 + (blk >> 3)) * 16;   // XCD-sliced: 512 rows/XCD
    int wrow = row_base + wv * 4;

    // W fragment -> registers, once (64 VGPRs; 2MB/XCD slice L2-resident)
    uint4 W[4][4];
#pragma unroll
    for (int r = 0; r < 4; ++r)
#pragma unroll
        for (int k4 = 0; k4 < 4; ++k4)
            W[r][k4] = Wp[(size_t)(wrow + r) * 256 + k4 * 64 + lane];

    const float SC = 1.f / (8192.f * 127.f);

    for (int l = 0; l < LLC; ++l) {
        if (l > 0) {
            // stage h: 16 coalesced relaxed-agent loads -> stride-1 LDS
            const unsigned* src = hq + (size_t)((l - 1) & 1) * 4096;
            unsigned sval[16];
#pragma unroll
            for (int k = 0; k < 16; ++k)
                sval[k] = __hip_atomic_load(src + t + k * 256, __ATOMIC_RELAXED,
                                            __HIP_MEMORY_SCOPE_AGENT);
#pragma unroll
            for (int k = 0; k < 16; ++k) hs[t + k * 256] = sval[k];
            __syncthreads();

            uint4 H[4][4];
#pragma unroll
            for (int b = 0; b < 4; ++b)
#pragma unroll
                for (int k4 = 0; k4 < 4; ++k4)
                    H[b][k4] = ((const uint4*)hs)[k4 * 256 + b * 64 + lane];
            int acc[4][4];
#pragma unroll
            for (int r = 0; r < 4; ++r)
#pragma unroll
                for (int b = 0; b < 4; ++b) acc[r][b] = 0;
#pragma unroll
            for (int k4 = 0; k4 < 4; ++k4)
#pragma unroll
                for (int r = 0; r < 4; ++r)
#pragma unroll
                    for (int b = 0; b < 4; ++b) {
                        acc[r][b] = SDOT4(W[r][k4].x, H[b][k4].x, acc[r][b]);
                        acc[r][b] = SDOT4(W[r][k4].y, H[b][k4].y, acc[r][b]);
                        acc[r][b] = SDOT4(W[r][k4].z, H[b][k4].z, acc[r][b]);
                        acc[r][b] = SDOT4(W[r][k4].w, H[b][k4].w, acc[r][b]);
                    }
#pragma unroll
            for (int r = 0; r < 4; ++r)
#pragma unroll
                for (int b = 0; b < 4; ++b) acc[r][b] = wred64(acc[r][b]);
            if (lane == 63) {
#pragma unroll
                for (int b = 0; b < 4; ++b) {
                    int4 q = { acc[0][b], acc[1][b], acc[2][b], acc[3][b] };
                    *(int4*)&red[wv][b * 4] = q;   // red[wv][b*4+rr]
                }
            }
        }
        // tail: 16 lanes/wave produce 4 rows x 4 batches (same-wave LDS dep)
        if (lane < 16) {
            int b = lane >> 2, rr = lane & 3;
            int row = wrow + rr;
            float a = (l > 0) ? (float)red[wv][lane] * SC : 0.f;
            float pre = a + xp[(size_t)(l * 4 + b) * NN + row];
            float hnew = tanhf(pre);
            if (l == LLC - 1) hfin[(size_t)b * NN + row] = hnew;
            int q = (int)rintf(hnew * 127.f);
            hpk[wv][b][rr] = (unsigned char)(q & 0xff);
        }
        if (l < LLC - 1) {
            if (lane < 4) {
                int b = lane;
                unsigned d = *(const unsigned*)&hpk[wv][b][0];
                int hk = (row_base >> 2) + wv;          // h-dword index (rows 4hk..4hk+3)
                int phys = ((hk >> 2) & 3) * 1024 + b * 256 + (hk >> 4) * 4 + (hk & 3);
                __hip_atomic_store(hq + (size_t)(l & 1) * 4096 + phys, d,
                                   __ATOMIC_RELAXED, __HIP_MEMORY_SCOPE_AGENT);
            }
            // ---- all-relaxed grid barrier (no wbl2/inv anywhere) ----
            __syncthreads();                   // s_waitcnt vmcnt(0): h at coherence pt
            if (t == 0) {
                int g = blk & 7;
                int old = __hip_atomic_fetch_add(&bar[g * 32], 1, __ATOMIC_RELAXED,
                                                 __HIP_MEMORY_SCOPE_AGENT);
                if ((old & 31) == 31)          // last of 32-block group this step
                    __hip_atomic_fetch_add(&bar[256], 1, __ATOMIC_RELAXED,
                                           __HIP_MEMORY_SCOPE_AGENT);
                int target = 8 * (l + 1);
                while (__hip_atomic_load(&bar[256], __ATOMIC_RELAXED,
                                         __HIP_MEMORY_SCOPE_AGENT) < target)
                    __builtin_amdgcn_s_sleep(2);
            }
            __syncthreads();
        }
    }
}

// ---- out[b,n,k] = sigmoid( gelu(res.dW[k]+db) * gelu(Emb) ), LDS-staged ----
__global__ __launch_bounds__(256) void k_final(const float* __restrict__ res,
                                               const float* __restrict__ dW,
                                               const float* __restrict__ db,
                                               const float* __restrict__ hfin,
                                               float* __restrict__ out) {
    __shared__ float4 sres4[512];          // 16 rows x 128
    __shared__ float sdw[10 * 132];        // pad 132: kills bank conflict
    int t = threadIdx.x;
    int row0 = blockIdx.x * 16;
    {
        const float4* src = (const float4*)(res + (size_t)row0 * 128);
        sres4[t] = src[t];
        sres4[t + 256] = src[t + 256];
    }
    for (int i = t; i < 1280; i += 256) { int k = i >> 7, c = i & 127; sdw[k * 132 + c] = dW[i]; }
    __syncthreads();
    int r = t >> 4, k = t & 15;
    if (k < 10) {
        const float* rr = (const float*)sres4 + r * 128;
        const float* wk = sdw + k * 132;
        float acc = 0.f;
#pragma unroll
        for (int c = 0; c < 128; c += 4) {
            float4 a = *(const float4*)(rr + c);
            float4 w = *(const float4*)(wk + c);
            acc += a.x * w.x + a.y * w.y + a.z * w.z + a.w * w.w;
        }
        float pre = acc + db[k];
        int grow = row0 + r;
        int b = grow >> 12, n = grow & 4095;
        float e = hfin[(size_t)b * NN + n];
        float g1 = 0.5f * pre * (1.f + erff(pre * 0.70710678118f));
        float ge = 0.5f * e * (1.f + erff(e * 0.70710678118f));
        out[(size_t)grow * 10 + k] = 1.f / (1.f + __expf(-g1 * ge));
    }
}

extern "C" void kernel_launch(void* const* d_in, const int* in_sizes, int n_in,
                              void* d_out, int out_size, void* d_ws, size_t ws_size,
                              hipStream_t stream) {
    const int*   phi1_idx = (const int*)d_in[0];
    const float* phi1_val = (const float*)d_in[1];
    const int*   inv1_idx = (const int*)d_in[2];
    const float* inv1_val = (const float*)d_in[3];
    const int*   phi2_idx = (const int*)d_in[4];
    const float* phi2_val = (const float*)d_in[5];
    const int*   inv2_idx = (const int*)d_in[6];
    const float* inv2_val = (const float*)d_in[7];
    const float* fea      = (const float*)d_in[8];
    const int*   joblst   = (const int*)d_in[9];
    const float* W1       = (const float*)d_in[10];
    const float* d1       = (const float*)d_in[11];
    const float* W2       = (const float*)d_in[12];
    const float* d2       = (const float*)d_in[13];
    const float* W_ih     = (const float*)d_in[14];
    const float* W_hh     = (const float*)d_in[15];
    const float* b_ih     = (const float*)d_in[16];
    const float* b_hh     = (const float*)d_in[17];
    const float* dense_W  = (const float*)d_in[18];
    const float* dense_b  = (const float*)d_in[19];
    const float* item_emb = (const float*)d_in[20];

    float* ws = (float*)d_ws;                       // slot = 4B
    unsigned short* filt1 = (unsigned short*)ws;            // 1,048,576 slots
    unsigned short* filt2 = (unsigned short*)(ws + 1048576);
    unsigned short* y1    = (unsigned short*)(ws + 2097152);
    unsigned short* y2    = (unsigned short*)(ws + 3145728);
    float* res  = ws + 4194304;                     // 2,097,152 slots
    float* xp   = ws + 6291456;                     // 819,200
    float* hfin = ws + 7110656;                     // 16,384
    unsigned* hq  = (unsigned*)(ws + 7127040);      // 8,192 (2 x 4096 dwords)
    uint4* w8p = (uint4*)(ws + 7135232);            // 16MB repacked int8 W
    int*   counts = (int*)(ws + 11329536);          // 65,536
    int*   rowptr = (int*)(ws + 11395072);          // 65,552
    int*   cursor = (int*)(ws + 11460624);          // 65,536
    unsigned* ep  = (unsigned*)(ws + 11526160);     // 1,048,576 (packed col|val)
    int*   bar    = (int*)(ws + 12574736);          // 257 ints (barrier counters)

    hipMemsetAsync(counts, 0, 16 * 4096 * sizeof(int), stream);
    hipMemsetAsync(bar, 0, 2048, stream);

    k_w8<<<4096, 256, 0, stream>>>(W_hh, w8p);
    k_filt<<<1024, 128, 0, stream>>>(fea, W1, W2, filt1, filt2);
    k_xproj<<<dim3(16, 25), 256, 0, stream>>>(item_emb, joblst, W_ih, b_ih, b_hh, xp);

    k_hist<<<256, 256, 0, stream>>>(inv1_idx, phi1_idx, inv2_idx, phi2_idx, counts);
    k_scan<<<16, 256, 0, stream>>>(counts, rowptr, cursor);
    k_scatter<<<4096, 256, 0, stream>>>(inv1_idx, phi1_idx, inv2_idx, phi2_idx,
                                        inv1_val, phi1_val, inv2_val, phi2_val,
                                        d1, d2, cursor, ep);

    k_gather1<<<32768, 128, 0, stream>>>(rowptr, ep, filt1, filt2, y1, y2);
    k_gather2<<<16384, 128, 0, stream>>>(rowptr, ep, y1, y2, res);

    // whole RNN: persistent kernel, REGULAR launch (grid <= resident capacity,
    // so the internal spin barrier is deadlock-free without cooperative launch)
    k_rnn_all<<<256, 256, 0, stream>>>(w8p, xp, hq, hfin, bar);

    k_final<<<1024, 256, 0, stream>>>(res, dense_W, dense_b, hfin, (float*)d_out);
}